// Round 4
// baseline (358.618 us; speedup 1.0000x reference)
//
#include <hip/hip_runtime.h>
#include <cstdint>

#define T_LEN 4096
#define BATCH 4
#define DIM   1024
#define NH    8
#define HDIM  128
#define ROWS  16384   // BATCH * T_LEN

typedef __bf16 bf16x8 __attribute__((ext_vector_type(8)));
typedef float  f32x4  __attribute__((ext_vector_type(4)));

__device__ __forceinline__ unsigned short f2bf(float f) {
  union { float f; unsigned u; } a; a.f = f;
  unsigned u = a.u;
  u += 0x7fff + ((u >> 16) & 1);   // RNE
  return (unsigned short)(u >> 16);
}
__device__ __forceinline__ float bf2f(unsigned short h) {
  union { unsigned u; float f; } a; a.u = ((unsigned)h) << 16;
  return a.f;
}

__device__ __forceinline__ void gld_lds16(const unsigned short* g, unsigned short* l) {
  __builtin_amdgcn_global_load_lds(
      (const __attribute__((address_space(1))) unsigned int*)g,
      (__attribute__((address_space(3))) unsigned int*)l, 16, 0, 0);
}

// ---------------- LayerNorm: x (T,B,D) fp32 -> xn, xtn (B*T, D) bf16 ----------------
__global__ __launch_bounds__(256) void ln_kernel(
    const float* __restrict__ x, const float* __restrict__ nw, const float* __restrict__ nb,
    const float* __restrict__ tw, const float* __restrict__ tb,
    unsigned short* __restrict__ xn, unsigned short* __restrict__ xtn) {
  int row = blockIdx.x;               // t*B + b
  int t = row >> 2, b = row & 3;
  int tid = threadIdx.x;
  const float4 v = ((const float4*)(x + (size_t)row * DIM))[tid];
  float s  = v.x + v.y + v.z + v.w;
  float s2 = v.x*v.x + v.y*v.y + v.z*v.z + v.w*v.w;
#pragma unroll
  for (int o = 32; o; o >>= 1) { s += __shfl_xor(s, o); s2 += __shfl_xor(s2, o); }
  __shared__ float red[8];
  int wv = tid >> 6;
  if ((tid & 63) == 0) { red[wv] = s; red[4 + wv] = s2; }
  __syncthreads();
  s  = red[0] + red[1] + red[2] + red[3];
  s2 = red[4] + red[5] + red[6] + red[7];
  float mean = s * (1.0f / DIM);
  float var  = s2 * (1.0f / DIM) - mean * mean;
  float rstd = rsqrtf(var + 1e-5f);
  size_t orow = ((size_t)b * T_LEN + t) * DIM;
  int c0 = tid * 4;
  float xv[4] = {v.x, v.y, v.z, v.w};
  union { unsigned short u[4]; uint2 d; } o1, o2;
#pragma unroll
  for (int j = 0; j < 4; ++j) {
    int c = c0 + j;
    float xh = (xv[j] - mean) * rstd;
    o1.u[j] = f2bf(xh * nw[c] + nb[c]);
    o2.u[j] = f2bf(xh * tw[c] + tb[c]);
  }
  *(uint2*)(xn  + orow + c0) = o1.d;
  *(uint2*)(xtn + orow + c0) = o2.d;
}

// ---------------- Convert Wq,Wk,Wv fp32 -> bf16 (concatenated) ----------------
__global__ __launch_bounds__(256) void wconv(
    const float* __restrict__ Wq, const float* __restrict__ Wk, const float* __restrict__ Wv,
    unsigned short* __restrict__ out) {
  int i4 = blockIdx.x * 256 + threadIdx.x;
  int w = i4 >> 18;
  const float* src = (w == 0) ? Wq : (w == 1 ? Wk : Wv);
  float4 v = ((const float4*)src)[i4 & 262143];
  union { unsigned short u[4]; uint2 d; } o;
  o.u[0] = f2bf(v.x); o.u[1] = f2bf(v.y); o.u[2] = f2bf(v.z); o.u[3] = f2bf(v.w);
  ((uint2*)out)[i4] = o.d;
}

// ---------------- QKV GEMM (swizzled LDS), templated per output mode ----------------
// MODE 0: q with fused head-dim softmax (row-major out)
// MODE 1: ksmT[b][c][t] = exp(k + bk), LDS-transposed coalesced store + Zk col-sum atomics
// MODE 2: vT[b][c][t]   = v + bv,      LDS-transposed coalesced store
template<int MODE>
__global__ __launch_bounds__(256) void qkv_gemm(
    const unsigned short* __restrict__ A, const unsigned short* __restrict__ W,
    const float* __restrict__ bias,
    unsigned short* __restrict__ outp, float* __restrict__ Zk) {
  int m0t = blockIdx.x * 128;   // m fastest-varying -> W tile stays L2-resident
  int n0 = blockIdx.y * 128;
  __shared__ __align__(16) unsigned short smem[128 * 136];  // 34.8 KB: As|Bs in loop, Ts in epilogue
  unsigned short* As = smem;
  unsigned short* Bs = smem + 8192;
  int tid = threadIdx.x;
  int wave = tid >> 6, lane = tid & 63;
  int wm = (wave >> 1) * 64, wn = (wave & 1) * 64;
  int l16 = lane & 15, kq = lane >> 4;
  int swz = l16 & 7;

  int srow = tid >> 3;
  int skk  = (((tid & 7) ^ ((tid >> 3) & 7)) * 8);   // XOR-swizzled source chunk
  const unsigned short* Ag = A + (size_t)(m0t + srow) * DIM + skk;
  const unsigned short* Wg = W + (size_t)(n0 + srow) * DIM + skk;
  unsigned short* Al = As + wave * 512;
  unsigned short* Bl = Bs + wave * 512;

  f32x4 acc[4][4] = {};

  for (int kt = 0; kt < DIM; kt += 64) {
#pragma unroll
    for (int p = 0; p < 4; ++p) {
      gld_lds16(Ag + (size_t)(p * 32) * DIM + kt, Al + p * 2048);
      gld_lds16(Wg + (size_t)(p * 32) * DIM + kt, Bl + p * 2048);
    }
    __syncthreads();
#pragma unroll
    for (int ks4 = 0; ks4 < 2; ++ks4) {
      int coff = (((kq + ks4 * 4) ^ swz) * 8);
      bf16x8 fa[4], fb[4];
#pragma unroll
      for (int i = 0; i < 4; ++i) {
        fa[i] = *(const bf16x8*)(As + (wm + i * 16 + l16) * 64 + coff);
        fb[i] = *(const bf16x8*)(Bs + (wn + i * 16 + l16) * 64 + coff);
      }
#pragma unroll
      for (int i = 0; i < 4; ++i)
#pragma unroll
        for (int j = 0; j < 4; ++j)
          acc[i][j] = __builtin_amdgcn_mfma_f32_16x16x32_bf16(fa[i], fb[j], acc[i][j], 0, 0, 0);
    }
    __syncthreads();
  }

  // bias
  float bcol[4];
#pragma unroll
  for (int j = 0; j < 4; ++j) bcol[j] = bias[n0 + wn + j * 16 + l16];
#pragma unroll
  for (int i = 0; i < 4; ++i)
#pragma unroll
    for (int j = 0; j < 4; ++j)
#pragma unroll
      for (int r = 0; r < 4; ++r) acc[i][j][r] += bcol[j];

  if (MODE == 0) {
    // fused softmax over head-dim: this block's 128 cols == one head
    float* redm = (float*)smem;
    float* reds = redm + 256;
#pragma unroll
    for (int i = 0; i < 4; ++i) {
#pragma unroll
      for (int r = 0; r < 4; ++r) {
        float pm = acc[i][0][r];
#pragma unroll
        for (int j = 1; j < 4; ++j) pm = fmaxf(pm, acc[i][j][r]);
        pm = fmaxf(pm, __shfl_xor(pm, 1));
        pm = fmaxf(pm, __shfl_xor(pm, 2));
        pm = fmaxf(pm, __shfl_xor(pm, 4));
        pm = fmaxf(pm, __shfl_xor(pm, 8));
        float ps = 0.0f;
#pragma unroll
        for (int j = 0; j < 4; ++j) ps += __expf(acc[i][j][r] - pm);
        ps += __shfl_xor(ps, 1);
        ps += __shfl_xor(ps, 2);
        ps += __shfl_xor(ps, 4);
        ps += __shfl_xor(ps, 8);
        if (l16 == 0) {
          int lrow = wm + i * 16 + kq * 4 + r;
          redm[lrow * 2 + (wave & 1)] = pm;
          reds[lrow * 2 + (wave & 1)] = ps;
        }
      }
    }
    __syncthreads();
#pragma unroll
    for (int i = 0; i < 4; ++i) {
#pragma unroll
      for (int r = 0; r < 4; ++r) {
        int lrow = wm + i * 16 + kq * 4 + r;
        float ma = redm[lrow * 2], mb = redm[lrow * 2 + 1];
        float sa = reds[lrow * 2], sb = reds[lrow * 2 + 1];
        float M = fmaxf(ma, mb);
        float inv = 1.0f / (sa * __expf(ma - M) + sb * __expf(mb - M));
        size_t gr = (size_t)(m0t + lrow) * DIM;
#pragma unroll
        for (int j = 0; j < 4; ++j) {
          int col = n0 + wn + j * 16 + l16;
          outp[gr + col] = f2bf(__expf(acc[i][j][r] - M) * inv);
        }
      }
    }
  } else {
    // LDS transpose: Ts[col][t], stride 136 (keeps uint4 alignment: 136*2=272 B ≡ 0 mod 16)
    unsigned short* Ts = smem;
#pragma unroll
    for (int j = 0; j < 4; ++j) {
      int col = wn + j * 16 + l16;
#pragma unroll
      for (int i = 0; i < 4; ++i) {
        int t0 = wm + i * 16 + kq * 4;
        float v0 = acc[i][j][0], v1 = acc[i][j][1], v2 = acc[i][j][2], v3 = acc[i][j][3];
        if (MODE == 1) { v0 = __expf(v0); v1 = __expf(v1); v2 = __expf(v2); v3 = __expf(v3); }
        unsigned lo = (unsigned)f2bf(v0) | ((unsigned)f2bf(v1) << 16);
        unsigned hi = (unsigned)f2bf(v2) | ((unsigned)f2bf(v3) << 16);
        *(unsigned*)(Ts + col * 136 + t0)     = lo;
        *(unsigned*)(Ts + col * 136 + t0 + 2) = hi;
      }
    }
    __syncthreads();
    int col_o = tid >> 1;
    int th = (tid & 1) * 64;
    int b = m0t >> 12, tb = m0t & 4095;
    unsigned short* cp = outp + ((size_t)b * DIM + n0 + col_o) * T_LEN + tb + th;
    float zs = 0.0f;
#pragma unroll
    for (int c = 0; c < 8; ++c) {
      uint4 d = *(const uint4*)(Ts + col_o * 136 + th + c * 8);
      *(uint4*)(cp + c * 8) = d;
      if (MODE == 1) {
        const unsigned short* u = (const unsigned short*)&d;
#pragma unroll
        for (int e = 0; e < 8; ++e) zs += bf2f(u[e]);
      }
    }
    if (MODE == 1) {
      zs += __shfl_xor(zs, 1);
      if ((tid & 1) == 0) atomicAdd(&Zk[b * DIM + n0 + col_o], zs);
    }
  }
}

// ---------------- att GEMM: attT[bh][l][d] += sum_t vT[l][t]*ksmT[d][t]; split-K=16 ----------------
__global__ __launch_bounds__(256) void att_gemm(
    const unsigned short* __restrict__ vT, const unsigned short* __restrict__ ksmT,
    float* __restrict__ attT) {
  int kc = blockIdx.x;   // 0..15 (t chunks of 256)
  int bh = blockIdx.y;
  const unsigned short* Arow = vT   + (size_t)bh * HDIM * T_LEN;
  const unsigned short* Brow = ksmT + (size_t)bh * HDIM * T_LEN;
  __shared__ __align__(16) unsigned short As[128 * 64];
  __shared__ __align__(16) unsigned short Bs[128 * 64];
  int tid = threadIdx.x;
  int wave = tid >> 6, lane = tid & 63;
  int wm = (wave >> 1) * 64, wn = (wave & 1) * 64;
  int l16 = lane & 15, kq = lane >> 4;
  int swz = l16 & 7;
  int srow = tid >> 3;
  int skk = (((tid & 7) ^ ((tid >> 3) & 7)) * 8);
  const unsigned short* Ag = Arow + (size_t)srow * T_LEN + skk;
  const unsigned short* Bg = Brow + (size_t)srow * T_LEN + skk;
  unsigned short* Al = As + wave * 512;
  unsigned short* Bl = Bs + wave * 512;
  f32x4 acc[4][4] = {};
  int kbeg = kc * 256;
  for (int kt = kbeg; kt < kbeg + 256; kt += 64) {
#pragma unroll
    for (int p = 0; p < 4; ++p) {
      gld_lds16(Ag + (size_t)(p * 32) * T_LEN + kt, Al + p * 2048);
      gld_lds16(Bg + (size_t)(p * 32) * T_LEN + kt, Bl + p * 2048);
    }
    __syncthreads();
#pragma unroll
    for (int ks4 = 0; ks4 < 2; ++ks4) {
      int coff = (((kq + ks4 * 4) ^ swz) * 8);
      bf16x8 fa[4], fb[4];
#pragma unroll
      for (int i = 0; i < 4; ++i) {
        fa[i] = *(const bf16x8*)(As + (wm + i * 16 + l16) * 64 + coff);
        fb[i] = *(const bf16x8*)(Bs + (wn + i * 16 + l16) * 64 + coff);
      }
#pragma unroll
      for (int i = 0; i < 4; ++i)
#pragma unroll
        for (int j = 0; j < 4; ++j)
          acc[i][j] = __builtin_amdgcn_mfma_f32_16x16x32_bf16(fa[i], fb[j], acc[i][j], 0, 0, 0);
    }
    __syncthreads();
  }
#pragma unroll
  for (int j = 0; j < 4; ++j) {
    int col = wn + j * 16 + l16;
#pragma unroll
    for (int i = 0; i < 4; ++i) {
      int rb = wm + i * 16 + kq * 4;
#pragma unroll
      for (int r = 0; r < 4; ++r)
        atomicAdd(attT + (size_t)bh * 16384 + (size_t)(rb + r) * 128 + col, acc[i][j][r]);
    }
  }
}

// ---------------- att normalize by Z[d] + cast to bf16 ----------------
__global__ __launch_bounds__(256) void attcvt(
    const float* __restrict__ attT, const float* __restrict__ Zk,
    unsigned short* __restrict__ attbf) {
  int idx = blockIdx.x * 256 + threadIdx.x;
  int bh = idx >> 14;
  int b = bh >> 3, h = bh & 7;
  int d = idx & 127;
  float z = Zk[b * DIM + h * HDIM + d];
  attbf[idx] = f2bf(attT[idx] / z);
}

// ---------------- y GEMM ----------------
__global__ __launch_bounds__(256) void y_gemm(
    const unsigned short* __restrict__ qsm, const unsigned short* __restrict__ attbf,
    float* __restrict__ out) {
  int h = blockIdx.y;
  int m0t = blockIdx.x * 128;
  int b = m0t >> 12;
  int bh = b * 8 + h;
  const unsigned short* Brow = attbf + (size_t)bh * 16384;
  __shared__ __align__(16) unsigned short As[128 * 64];
  __shared__ __align__(16) unsigned short Bs[128 * 64];
  int tid = threadIdx.x;
  int wave = tid >> 6, lane = tid & 63;
  int wm = (wave >> 1) * 64, wn = (wave & 1) * 64;
  int l16 = lane & 15, kq = lane >> 4;
  int swz = l16 & 7;
  int srow = tid >> 3;
  int skk = (((tid & 7) ^ ((tid >> 3) & 7)) * 8);
  const unsigned short* Ag = qsm + (size_t)(m0t + srow) * DIM + h * HDIM + skk;
  const unsigned short* Bg = Brow + (size_t)srow * HDIM + skk;
  unsigned short* Al = As + wave * 512;
  unsigned short* Bl = Bs + wave * 512;
  f32x4 acc[4][4] = {};
  for (int kt = 0; kt < HDIM; kt += 64) {
#pragma unroll
    for (int p = 0; p < 4; ++p) {
      gld_lds16(Ag + (size_t)(p * 32) * DIM + kt, Al + p * 2048);
      gld_lds16(Bg + (size_t)(p * 32) * HDIM + kt, Bl + p * 2048);
    }
    __syncthreads();
#pragma unroll
    for (int ks4 = 0; ks4 < 2; ++ks4) {
      int coff = (((kq + ks4 * 4) ^ swz) * 8);
      bf16x8 fa[4], fb[4];
#pragma unroll
      for (int i = 0; i < 4; ++i) {
        fa[i] = *(const bf16x8*)(As + (wm + i * 16 + l16) * 64 + coff);
        fb[i] = *(const bf16x8*)(Bs + (wn + i * 16 + l16) * 64 + coff);
      }
#pragma unroll
      for (int i = 0; i < 4; ++i)
#pragma unroll
        for (int j = 0; j < 4; ++j)
          acc[i][j] = __builtin_amdgcn_mfma_f32_16x16x32_bf16(fa[i], fb[j], acc[i][j], 0, 0, 0);
    }
    __syncthreads();
  }
#pragma unroll
  for (int j = 0; j < 4; ++j) {
    int col = wn + j * 16 + l16;
#pragma unroll
    for (int i = 0; i < 4; ++i) {
      int rb = wm + i * 16 + kq * 4;
#pragma unroll
      for (int r = 0; r < 4; ++r)
        out[(size_t)(m0t + rb + r) * DIM + h * HDIM + col] = acc[i][j][r];
    }
  }
}

extern "C" void kernel_launch(void* const* d_in, const int* in_sizes, int n_in,
                              void* d_out, int out_size, void* d_ws, size_t ws_size,
                              hipStream_t stream) {
  const float* x  = (const float*)d_in[0];
  const float* nw = (const float*)d_in[1];
  const float* nb = (const float*)d_in[2];
  const float* tw = (const float*)d_in[3];
  const float* tb = (const float*)d_in[4];
  const float* Wq = (const float*)d_in[5];
  const float* bq = (const float*)d_in[6];
  const float* Wk = (const float*)d_in[7];
  const float* bk = (const float*)d_in[8];
  const float* Wv = (const float*)d_in[9];
  const float* bv = (const float*)d_in[10];
  float* out = (float*)d_out;

  char* ws = (char*)d_ws;
  unsigned short* xn   = (unsigned short*)(ws);                 // 32 MB
  unsigned short* xtn  = (unsigned short*)(ws + 33554432);      // 32 MB
  unsigned short* q    = (unsigned short*)(ws + 67108864);      // 32 MB (softmaxed in epilogue)
  unsigned short* ksmT = (unsigned short*)(ws + 100663296);     // 32 MB  exp(k) transposed
  unsigned short* vT   = (unsigned short*)(ws + 134217728);     // 32 MB  v transposed
  unsigned short* wbf  = (unsigned short*)(ws + 167772160);     // 6 MB
  float* attT          = (float*)(ws + 174063616);              // 2 MB
  float* Zk            = (float*)(ws + 176160768);              // 16 KB (adjacent to attT for one memset)
  unsigned short* attbf= (unsigned short*)(ws + 176177152);     // 1 MB

  // zero attT (2 MB) + Zk (16 KB) in one shot
  (void)hipMemsetAsync(attT, 0, 32 * 128 * 128 * 4 + BATCH * DIM * 4, stream);
  ln_kernel<<<ROWS, 256, 0, stream>>>(x, nw, nb, tw, tb, xn, xtn);
  wconv<<<3072, 256, 0, stream>>>(Wq, Wk, Wv, wbf);
  qkv_gemm<1><<<dim3(128, 8), 256, 0, stream>>>(xtn, wbf + (size_t)1 * DIM * DIM, bk, ksmT, Zk);
  qkv_gemm<2><<<dim3(128, 8), 256, 0, stream>>>(xtn, wbf + (size_t)2 * DIM * DIM, bv, vT, Zk);
  qkv_gemm<0><<<dim3(128, 8), 256, 0, stream>>>(xn,  wbf,                         bq, q,  Zk);
  att_gemm<<<dim3(16, 32), 256, 0, stream>>>(vT, ksmT, attT);
  attcvt<<<2048, 256, 0, stream>>>(attT, Zk, attbf);
  y_gemm<<<dim3(128, 8), 256, 0, stream>>>(q, attbf, out);
}

// Round 5
// 343.843 us; speedup vs baseline: 1.0430x; 1.0430x over previous
//
#include <hip/hip_runtime.h>
#include <cstdint>

#define T_LEN 4096
#define BATCH 4
#define DIM   1024
#define NH    8
#define HDIM  128
#define ROWS  16384   // BATCH * T_LEN

typedef __bf16 bf16x8 __attribute__((ext_vector_type(8)));
typedef float  f32x4  __attribute__((ext_vector_type(4)));

__device__ __forceinline__ unsigned short f2bf(float f) {
  union { float f; unsigned u; } a; a.f = f;
  unsigned u = a.u;
  u += 0x7fff + ((u >> 16) & 1);   // RNE
  return (unsigned short)(u >> 16);
}
__device__ __forceinline__ float bf2f(unsigned short h) {
  union { unsigned u; float f; } a; a.u = ((unsigned)h) << 16;
  return a.f;
}

__device__ __forceinline__ void gld_lds16(const unsigned short* g, unsigned short* l) {
  __builtin_amdgcn_global_load_lds(
      (const __attribute__((address_space(1))) unsigned int*)g,
      (__attribute__((address_space(3))) unsigned int*)l, 16, 0, 0);
}

// ---------------- prep: LayerNorm (blocks < ROWS) + weight fp32->bf16 convert ----------------
__global__ __launch_bounds__(256) void prep(
    const float* __restrict__ x, const float* __restrict__ nw, const float* __restrict__ nb,
    const float* __restrict__ tw, const float* __restrict__ tb,
    unsigned short* __restrict__ xn, unsigned short* __restrict__ xtn,
    const float* __restrict__ Wq, const float* __restrict__ Wk, const float* __restrict__ Wv,
    unsigned short* __restrict__ wbf) {
  int tid = threadIdx.x;
  if (blockIdx.x < ROWS) {
    int row = blockIdx.x;               // t*B + b
    int t = row >> 2, b = row & 3;
    const float4 v = ((const float4*)(x + (size_t)row * DIM))[tid];
    float s  = v.x + v.y + v.z + v.w;
    float s2 = v.x*v.x + v.y*v.y + v.z*v.z + v.w*v.w;
#pragma unroll
    for (int o = 32; o; o >>= 1) { s += __shfl_xor(s, o); s2 += __shfl_xor(s2, o); }
    __shared__ float red[8];
    int wv = tid >> 6;
    if ((tid & 63) == 0) { red[wv] = s; red[4 + wv] = s2; }
    __syncthreads();
    s  = red[0] + red[1] + red[2] + red[3];
    s2 = red[4] + red[5] + red[6] + red[7];
    float mean = s * (1.0f / DIM);
    float var  = s2 * (1.0f / DIM) - mean * mean;
    float rstd = rsqrtf(var + 1e-5f);
    size_t orow = ((size_t)b * T_LEN + t) * DIM;
    int c0 = tid * 4;
    float xv[4] = {v.x, v.y, v.z, v.w};
    union { unsigned short u[4]; uint2 d; } o1, o2;
#pragma unroll
    for (int j = 0; j < 4; ++j) {
      int c = c0 + j;
      float xh = (xv[j] - mean) * rstd;
      o1.u[j] = f2bf(xh * nw[c] + nb[c]);
      o2.u[j] = f2bf(xh * tw[c] + tb[c]);
    }
    *(uint2*)(xn  + orow + c0) = o1.d;
    *(uint2*)(xtn + orow + c0) = o2.d;
  } else {
    int i4 = (blockIdx.x - ROWS) * 256 + tid;   // float4 units, 786432 total
    int w = i4 >> 18;
    const float* src = (w == 0) ? Wq : (w == 1 ? Wk : Wv);
    float4 v = ((const float4*)src)[i4 & 262143];
    union { unsigned short u[4]; uint2 d; } o;
    o.u[0] = f2bf(v.x); o.u[1] = f2bf(v.y); o.u[2] = f2bf(v.z); o.u[3] = f2bf(v.w);
    ((uint2*)wbf)[i4] = o.d;
  }
}

// ---------------- QKV GEMM (swizzled LDS), z = 0:q(softmax) 1:ksmT=exp(k) 2:vT ----------------
// z!=0 outputs transposed [b][col][t] via two-pass 32KB LDS transpose; z==1 also
// accumulates Zk[b][col] partial sums via one atomic per column per block.
__global__ __launch_bounds__(256) void qkv_gemm(
    const unsigned short* __restrict__ xn, const unsigned short* __restrict__ xtn,
    const unsigned short* __restrict__ wbf,
    const float* __restrict__ bq, const float* __restrict__ bk, const float* __restrict__ bv,
    unsigned short* __restrict__ qo, unsigned short* __restrict__ ko, unsigned short* __restrict__ vo,
    float* __restrict__ Zk) {
  int z = blockIdx.z;
  const unsigned short* A = (z == 0) ? xn : xtn;
  const unsigned short* W = wbf + (size_t)z * DIM * DIM;
  const float* bias = (z == 0) ? bq : (z == 1 ? bk : bv);
  unsigned short* outp = (z == 0) ? qo : (z == 1 ? ko : vo);

  int m0t = blockIdx.x * 128;   // m fastest-varying -> W tile stays L2-resident
  int n0 = blockIdx.y * 128;
  __shared__ __align__(16) unsigned short smem[16384];   // exactly 32 KB
  unsigned short* As = smem;
  unsigned short* Bs = smem + 8192;
  int tid = threadIdx.x;
  int wave = tid >> 6, lane = tid & 63;
  int wm = (wave >> 1) * 64, wn = (wave & 1) * 64;
  int l16 = lane & 15, kq = lane >> 4;
  int swz = l16 & 7;

  int srow = tid >> 3;
  int skk  = (((tid & 7) ^ ((tid >> 3) & 7)) * 8);   // XOR-swizzled source chunk
  const unsigned short* Ag = A + (size_t)(m0t + srow) * DIM + skk;
  const unsigned short* Wg = W + (size_t)(n0 + srow) * DIM + skk;
  unsigned short* Al = As + wave * 512;
  unsigned short* Bl = Bs + wave * 512;

  f32x4 acc[4][4] = {};

  for (int kt = 0; kt < DIM; kt += 64) {
#pragma unroll
    for (int p = 0; p < 4; ++p) {
      gld_lds16(Ag + (size_t)(p * 32) * DIM + kt, Al + p * 2048);
      gld_lds16(Wg + (size_t)(p * 32) * DIM + kt, Bl + p * 2048);
    }
    __syncthreads();
#pragma unroll
    for (int ks4 = 0; ks4 < 2; ++ks4) {
      int coff = (((kq + ks4 * 4) ^ swz) * 8);
      bf16x8 fa[4], fb[4];
#pragma unroll
      for (int i = 0; i < 4; ++i) {
        fa[i] = *(const bf16x8*)(As + (wm + i * 16 + l16) * 64 + coff);
        fb[i] = *(const bf16x8*)(Bs + (wn + i * 16 + l16) * 64 + coff);
      }
#pragma unroll
      for (int i = 0; i < 4; ++i)
#pragma unroll
        for (int j = 0; j < 4; ++j)
          acc[i][j] = __builtin_amdgcn_mfma_f32_16x16x32_bf16(fa[i], fb[j], acc[i][j], 0, 0, 0);
    }
    __syncthreads();
  }

  // bias
  float bcol[4];
#pragma unroll
  for (int j = 0; j < 4; ++j) bcol[j] = bias[n0 + wn + j * 16 + l16];
#pragma unroll
  for (int i = 0; i < 4; ++i)
#pragma unroll
    for (int j = 0; j < 4; ++j)
#pragma unroll
      for (int r = 0; r < 4; ++r) acc[i][j][r] += bcol[j];

  if (z == 0) {
    // fused softmax over head-dim: this block's 128 cols == one head
    float* redm = (float*)smem;
    float* reds = redm + 256;
#pragma unroll
    for (int i = 0; i < 4; ++i) {
#pragma unroll
      for (int r = 0; r < 4; ++r) {
        float pm = acc[i][0][r];
#pragma unroll
        for (int j = 1; j < 4; ++j) pm = fmaxf(pm, acc[i][j][r]);
        pm = fmaxf(pm, __shfl_xor(pm, 1));
        pm = fmaxf(pm, __shfl_xor(pm, 2));
        pm = fmaxf(pm, __shfl_xor(pm, 4));
        pm = fmaxf(pm, __shfl_xor(pm, 8));
        float ps = 0.0f;
#pragma unroll
        for (int j = 0; j < 4; ++j) ps += __expf(acc[i][j][r] - pm);
        ps += __shfl_xor(ps, 1);
        ps += __shfl_xor(ps, 2);
        ps += __shfl_xor(ps, 4);
        ps += __shfl_xor(ps, 8);
        if (l16 == 0) {
          int lrow = wm + i * 16 + kq * 4 + r;
          redm[lrow * 2 + (wave & 1)] = pm;
          reds[lrow * 2 + (wave & 1)] = ps;
        }
      }
    }
    __syncthreads();
#pragma unroll
    for (int i = 0; i < 4; ++i) {
#pragma unroll
      for (int r = 0; r < 4; ++r) {
        int lrow = wm + i * 16 + kq * 4 + r;
        float ma = redm[lrow * 2], mb = redm[lrow * 2 + 1];
        float sa = reds[lrow * 2], sb = reds[lrow * 2 + 1];
        float M = fmaxf(ma, mb);
        float inv = 1.0f / (sa * __expf(ma - M) + sb * __expf(mb - M));
        size_t gr = (size_t)(m0t + lrow) * DIM;
#pragma unroll
        for (int j = 0; j < 4; ++j) {
          int col = n0 + wn + j * 16 + l16;
          outp[gr + col] = f2bf(__expf(acc[i][j][r] - M) * inv);
        }
      }
    }
  } else {
    // two-pass LDS transpose within 32 KB: Ts[col][tt], tt in [0,64), stride 72 (18 KB)
    unsigned short* Ts = smem;
    int b = m0t >> 12, tb = m0t & 4095;
    bool doExp = (z == 1);
    float zs = 0.0f;
    int col_o = tid >> 1;
    int th = (tid & 1) * 32;
#pragma unroll
    for (int p = 0; p < 2; ++p) {
      __syncthreads();
      if ((wm >> 6) == p) {     // waves whose t-rows fall in this 64-t half
#pragma unroll
        for (int j = 0; j < 4; ++j) {
          int col = wn + j * 16 + l16;
#pragma unroll
          for (int i = 0; i < 4; ++i) {
            int tt = i * 16 + kq * 4;
            float v0 = acc[i][j][0], v1 = acc[i][j][1], v2 = acc[i][j][2], v3 = acc[i][j][3];
            if (doExp) { v0 = __expf(v0); v1 = __expf(v1); v2 = __expf(v2); v3 = __expf(v3); }
            unsigned lo = (unsigned)f2bf(v0) | ((unsigned)f2bf(v1) << 16);
            unsigned hi = (unsigned)f2bf(v2) | ((unsigned)f2bf(v3) << 16);
            *(unsigned*)(Ts + col * 72 + tt)     = lo;
            *(unsigned*)(Ts + col * 72 + tt + 2) = hi;
          }
        }
      }
      __syncthreads();
      unsigned short* cp = outp + ((size_t)b * DIM + n0 + col_o) * T_LEN + tb + p * 64 + th;
#pragma unroll
      for (int c = 0; c < 4; ++c) {
        uint4 d = *(const uint4*)(Ts + col_o * 72 + th + c * 8);
        *(uint4*)(cp + c * 8) = d;
        if (doExp) {
          const unsigned short* u = (const unsigned short*)&d;
#pragma unroll
          for (int e = 0; e < 8; ++e) zs += bf2f(u[e]);
        }
      }
    }
    if (doExp) {
      zs += __shfl_xor(zs, 1);
      if ((tid & 1) == 0) atomicAdd(&Zk[b * DIM + n0 + col_o], zs);
    }
  }
}

// ---------------- att GEMM: attT[bh][l][d] += sum_t vT[l][t]*ksmT[d][t]; split-K=16 ----------------
__global__ __launch_bounds__(256) void att_gemm(
    const unsigned short* __restrict__ vT, const unsigned short* __restrict__ ksmT,
    float* __restrict__ attT) {
  int kc = blockIdx.x;   // 0..15 (t chunks of 256)
  int bh = blockIdx.y;
  const unsigned short* Arow = vT   + (size_t)bh * HDIM * T_LEN;
  const unsigned short* Brow = ksmT + (size_t)bh * HDIM * T_LEN;
  __shared__ __align__(16) unsigned short As[128 * 64];
  __shared__ __align__(16) unsigned short Bs[128 * 64];
  int tid = threadIdx.x;
  int wave = tid >> 6, lane = tid & 63;
  int wm = (wave >> 1) * 64, wn = (wave & 1) * 64;
  int l16 = lane & 15, kq = lane >> 4;
  int swz = l16 & 7;
  int srow = tid >> 3;
  int skk = (((tid & 7) ^ ((tid >> 3) & 7)) * 8);
  const unsigned short* Ag = Arow + (size_t)srow * T_LEN + skk;
  const unsigned short* Bg = Brow + (size_t)srow * T_LEN + skk;
  unsigned short* Al = As + wave * 512;
  unsigned short* Bl = Bs + wave * 512;
  f32x4 acc[4][4] = {};
  int kbeg = kc * 256;
  for (int kt = kbeg; kt < kbeg + 256; kt += 64) {
#pragma unroll
    for (int p = 0; p < 4; ++p) {
      gld_lds16(Ag + (size_t)(p * 32) * T_LEN + kt, Al + p * 2048);
      gld_lds16(Bg + (size_t)(p * 32) * T_LEN + kt, Bl + p * 2048);
    }
    __syncthreads();
#pragma unroll
    for (int ks4 = 0; ks4 < 2; ++ks4) {
      int coff = (((kq + ks4 * 4) ^ swz) * 8);
      bf16x8 fa[4], fb[4];
#pragma unroll
      for (int i = 0; i < 4; ++i) {
        fa[i] = *(const bf16x8*)(As + (wm + i * 16 + l16) * 64 + coff);
        fb[i] = *(const bf16x8*)(Bs + (wn + i * 16 + l16) * 64 + coff);
      }
#pragma unroll
      for (int i = 0; i < 4; ++i)
#pragma unroll
        for (int j = 0; j < 4; ++j)
          acc[i][j] = __builtin_amdgcn_mfma_f32_16x16x32_bf16(fa[i], fb[j], acc[i][j], 0, 0, 0);
    }
    __syncthreads();
  }
#pragma unroll
  for (int j = 0; j < 4; ++j) {
    int col = wn + j * 16 + l16;
#pragma unroll
    for (int i = 0; i < 4; ++i) {
      int rb = wm + i * 16 + kq * 4;
#pragma unroll
      for (int r = 0; r < 4; ++r)
        atomicAdd(attT + (size_t)bh * 16384 + (size_t)(rb + r) * 128 + col, acc[i][j][r]);
    }
  }
}

// ---------------- att normalize by Z[d] + cast to bf16 ----------------
__global__ __launch_bounds__(256) void attcvt(
    const float* __restrict__ attT, const float* __restrict__ Zk,
    unsigned short* __restrict__ attbf) {
  int idx = blockIdx.x * 256 + threadIdx.x;
  int bh = idx >> 14;
  int b = bh >> 3, h = bh & 7;
  int d = idx & 127;
  float z = Zk[b * DIM + h * HDIM + d];
  attbf[idx] = f2bf(attT[idx] / z);
}

// ---------------- y GEMM ----------------
__global__ __launch_bounds__(256) void y_gemm(
    const unsigned short* __restrict__ qsm, const unsigned short* __restrict__ attbf,
    float* __restrict__ out) {
  int h = blockIdx.y;
  int m0t = blockIdx.x * 128;
  int b = m0t >> 12;
  int bh = b * 8 + h;
  const unsigned short* Brow = attbf + (size_t)bh * 16384;
  __shared__ __align__(16) unsigned short As[128 * 64];
  __shared__ __align__(16) unsigned short Bs[128 * 64];
  int tid = threadIdx.x;
  int wave = tid >> 6, lane = tid & 63;
  int wm = (wave >> 1) * 64, wn = (wave & 1) * 64;
  int l16 = lane & 15, kq = lane >> 4;
  int swz = l16 & 7;
  int srow = tid >> 3;
  int skk = (((tid & 7) ^ ((tid >> 3) & 7)) * 8);
  const unsigned short* Ag = qsm + (size_t)(m0t + srow) * DIM + h * HDIM + skk;
  const unsigned short* Bg = Brow + (size_t)srow * HDIM + skk;
  unsigned short* Al = As + wave * 512;
  unsigned short* Bl = Bs + wave * 512;
  f32x4 acc[4][4] = {};
  for (int kt = 0; kt < HDIM; kt += 64) {
#pragma unroll
    for (int p = 0; p < 4; ++p) {
      gld_lds16(Ag + (size_t)(p * 32) * DIM + kt, Al + p * 2048);
      gld_lds16(Bg + (size_t)(p * 32) * HDIM + kt, Bl + p * 2048);
    }
    __syncthreads();
#pragma unroll
    for (int ks4 = 0; ks4 < 2; ++ks4) {
      int coff = (((kq + ks4 * 4) ^ swz) * 8);
      bf16x8 fa[4], fb[4];
#pragma unroll
      for (int i = 0; i < 4; ++i) {
        fa[i] = *(const bf16x8*)(As + (wm + i * 16 + l16) * 64 + coff);
        fb[i] = *(const bf16x8*)(Bs + (wn + i * 16 + l16) * 64 + coff);
      }
#pragma unroll
      for (int i = 0; i < 4; ++i)
#pragma unroll
        for (int j = 0; j < 4; ++j)
          acc[i][j] = __builtin_amdgcn_mfma_f32_16x16x32_bf16(fa[i], fb[j], acc[i][j], 0, 0, 0);
    }
    __syncthreads();
  }
#pragma unroll
  for (int j = 0; j < 4; ++j) {
    int col = wn + j * 16 + l16;
#pragma unroll
    for (int i = 0; i < 4; ++i) {
      int rb = wm + i * 16 + kq * 4;
#pragma unroll
      for (int r = 0; r < 4; ++r)
        out[(size_t)(m0t + rb + r) * DIM + h * HDIM + col] = acc[i][j][r];
    }
  }
}

extern "C" void kernel_launch(void* const* d_in, const int* in_sizes, int n_in,
                              void* d_out, int out_size, void* d_ws, size_t ws_size,
                              hipStream_t stream) {
  const float* x  = (const float*)d_in[0];
  const float* nw = (const float*)d_in[1];
  const float* nb = (const float*)d_in[2];
  const float* tw = (const float*)d_in[3];
  const float* tb = (const float*)d_in[4];
  const float* Wq = (const float*)d_in[5];
  const float* bq = (const float*)d_in[6];
  const float* Wk = (const float*)d_in[7];
  const float* bk = (const float*)d_in[8];
  const float* Wv = (const float*)d_in[9];
  const float* bv = (const float*)d_in[10];
  float* out = (float*)d_out;

  char* ws = (char*)d_ws;
  unsigned short* xn   = (unsigned short*)(ws);                 // 32 MB
  unsigned short* xtn  = (unsigned short*)(ws + 33554432);      // 32 MB
  unsigned short* q    = (unsigned short*)(ws + 67108864);      // 32 MB (softmaxed in epilogue)
  unsigned short* ksmT = (unsigned short*)(ws + 100663296);     // 32 MB  exp(k) transposed
  unsigned short* vT   = (unsigned short*)(ws + 134217728);     // 32 MB  v transposed
  unsigned short* wbf  = (unsigned short*)(ws + 167772160);     // 6 MB
  float* attT          = (float*)(ws + 174063616);              // 2 MB
  float* Zk            = (float*)(ws + 176160768);              // 16 KB (adjacent to attT for one memset)
  unsigned short* attbf= (unsigned short*)(ws + 176177152);     // 1 MB

  // zero attT (2 MB) + Zk (16 KB) in one shot
  (void)hipMemsetAsync(attT, 0, 32 * 128 * 128 * 4 + BATCH * DIM * 4, stream);
  prep<<<ROWS + 3072, 256, 0, stream>>>(x, nw, nb, tw, tb, xn, xtn, Wq, Wk, Wv, wbf);
  qkv_gemm<<<dim3(128, 8, 3), 256, 0, stream>>>(xn, xtn, wbf, bq, bk, bv, q, ksmT, vT, Zk);
  att_gemm<<<dim3(16, 32), 256, 0, stream>>>(vT, ksmT, attT);
  attcvt<<<2048, 256, 0, stream>>>(attT, Zk, attbf);
  y_gemm<<<dim3(128, 8), 256, 0, stream>>>(q, attbf, out);
}